// Round 12
// baseline (657.056 us; speedup 1.0000x reference)
//
#include <hip/hip_runtime.h>
#include <hip/hip_bf16.h>

// Problem constants (from reference)
#define N_NODES 4096
#define IN_DIM  512
#define HID_DIM 256
#define OUT_DIM 64
#define PROP_STEP 10
#define MAX_DEG 128            // mean degree ~41; padded to multiple of 16
#define KSPLIT  4              // mlp1 split-K factor
#define MLP1_BLOCKS (64 * 4 * KSPLIT)   // 1024
#define PROP_BLOCKS 256        // 1 block/CU; co-residency trivially guaranteed
#define ROWS_PER_WAVE 4        // 4096 rows / (256 blocks * 4 waves)
#define LAM_CONST (1.0f/0.9f - 1.0f)
#define SCAD_A 3.7f

__device__ __forceinline__ ushort f2bf(float f) {
    unsigned u = __float_as_uint(f);
    unsigned r = (u + 0x7FFFu + ((u >> 16) & 1u)) >> 16;  // RNE
    return (ushort)r;
}
__device__ __forceinline__ unsigned pack2(float lo, float hi) {
    return (unsigned)f2bf(lo) | ((unsigned)f2bf(hi) << 16);
}
__device__ __forceinline__ float bflo(unsigned u) { return __uint_as_float(u << 16); }
__device__ __forceinline__ float bfhi(unsigned u) { return __uint_as_float(u & 0xFFFF0000u); }

__device__ __forceinline__ float wave_reduce_add(float v) {
#pragma unroll
    for (int off = 32; off > 0; off >>= 1) v += __shfl_xor(v, off, 64);
    return v;
}

// Lean grid barrier: every thread fences (release), block rep atomically
// arrives at agent scope, spins with s_sleep until all PROP_BLOCKS blocks of
// this phase arrived. Counter is monotone: target = phase*PROP_BLOCKS.
// This is what a kernel boundary does for visibility, minus launch/drain.
__device__ __forceinline__ void grid_barrier(int* cnt, int target) {
    __threadfence();                     // release my writes (L2 writeback)
    __syncthreads();                     // whole block done + fenced
    if (threadIdx.x == 0) {
        __hip_atomic_fetch_add(cnt, 1, __ATOMIC_ACQ_REL, __HIP_MEMORY_SCOPE_AGENT);
        while (__hip_atomic_load(cnt, __ATOMIC_ACQUIRE, __HIP_MEMORY_SCOPE_AGENT) < target)
            __builtin_amdgcn_s_sleep(2);
    }
    __syncthreads();
    __threadfence();                     // acquire: invalidate stale cache
}

// ---------------------------------------------------------------------------
// Heterogeneous fused kernel: blocks [0, 1024) run the mlp1 split-K GEMM
// (issued FIRST to seed the CUs); blocks [1024, 1024+4096) each build one
// ELL adjacency row from dense fp32 A. Disjoint inputs/outputs; overlap.
// ---------------------------------------------------------------------------
__global__ __launch_bounds__(256) void build_mlp1(
    const float* __restrict__ A, const float* __restrict__ F,
    const float* __restrict__ W1, float* __restrict__ Hp,
    int* __restrict__ ell, int* __restrict__ deg,
    float* __restrict__ invD, float* __restrict__ invDsq)
{
    if (blockIdx.x < MLP1_BLOCKS) {
        __shared__ float sA[16][68];
        __shared__ float sB[16][68];
        int bid = blockIdx.x;
        int t  = threadIdx.x;
        int m0 = (bid & 63) * 64;
        int n0 = ((bid >> 6) & 3) * 64;
        int kp = bid >> 8;                 // 0..3
        int tm = (t & 15) * 4;
        int tn = (t >> 4) * 4;
        int ar = t >> 2;
        int ac = (t & 3) * 4;
        int br = t >> 4;
        int bc = (t & 15) * 4;
        float acc[4][4] = {};
        int k0 = kp * (IN_DIM / KSPLIT);
        for (int kc = k0; kc < k0 + IN_DIM / KSPLIT; kc += 16) {
            float4 va = *(const float4*)(F  + (size_t)(m0 + ar) * IN_DIM + kc + ac);
            float4 vb = *(const float4*)(W1 + (size_t)(kc + br) * HID_DIM + n0 + bc);
            __syncthreads();
            sA[ac + 0][ar] = va.x;
            sA[ac + 1][ar] = va.y;
            sA[ac + 2][ar] = va.z;
            sA[ac + 3][ar] = va.w;
            *(float4*)&sB[br][bc] = vb;
            __syncthreads();
#pragma unroll
            for (int k = 0; k < 16; k++) {
                float4 a = *(const float4*)&sA[k][tm];
                float4 b = *(const float4*)&sB[k][tn];
                acc[0][0] += a.x * b.x; acc[0][1] += a.x * b.y; acc[0][2] += a.x * b.z; acc[0][3] += a.x * b.w;
                acc[1][0] += a.y * b.x; acc[1][1] += a.y * b.y; acc[1][2] += a.y * b.z; acc[1][3] += a.y * b.w;
                acc[2][0] += a.z * b.x; acc[2][1] += a.z * b.y; acc[2][2] += a.z * b.z; acc[2][3] += a.z * b.w;
                acc[3][0] += a.w * b.x; acc[3][1] += a.w * b.y; acc[3][2] += a.w * b.z; acc[3][3] += a.w * b.w;
            }
        }
        float* Hb = Hp + (size_t)kp * N_NODES * HID_DIM;
#pragma unroll
        for (int r = 0; r < 4; r++) {
            *(float4*)&Hb[(size_t)(m0 + tm + r) * HID_DIM + n0 + tn] =
                make_float4(acc[r][0], acc[r][1], acc[r][2], acc[r][3]);
        }
    } else {
        __shared__ int cnt;
        int i = blockIdx.x - MLP1_BLOCKS;
        int t = threadIdx.x;
        if (t == 0) cnt = 0;
        __syncthreads();
        const float4* row = (const float4*)(A + (size_t)i * N_NODES);
        for (int q = t; q < N_NODES / 4; q += 256) {
            float4 v = row[q];
            if (v.x != 0.0f) { int p = atomicAdd(&cnt, 1); if (p < MAX_DEG) ell[i * MAX_DEG + p] = q * 4 + 0; }
            if (v.y != 0.0f) { int p = atomicAdd(&cnt, 1); if (p < MAX_DEG) ell[i * MAX_DEG + p] = q * 4 + 1; }
            if (v.z != 0.0f) { int p = atomicAdd(&cnt, 1); if (p < MAX_DEG) ell[i * MAX_DEG + p] = q * 4 + 2; }
            if (v.w != 0.0f) { int p = atomicAdd(&cnt, 1); if (p < MAX_DEG) ell[i * MAX_DEG + p] = q * 4 + 3; }
        }
        __syncthreads();
        if (t == 0) {
            int c = cnt;
            if (c > MAX_DEG) c = MAX_DEG;
            deg[i] = c;
            int pad = (c + 15) & ~15;
            if (pad > MAX_DEG) pad = MAX_DEG;
            for (int p = c; p < pad; p++) ell[i * MAX_DEG + p] = i;  // self pad, masked later
            float d = (float)(cnt + 1);   // true degree + self loop
            invD[i] = 1.0f / d;
            invDsq[i] = rsqrtf(d);
        }
    }
}

// ---------------------------------------------------------------------------
// Fused reduce+mlp2: h = relu(sum_z Hp[z] + b1); F0 = h @ W2 + b2; + first
// normalize -> packed bf16 Fu row + fp32 norm. W2 staged in LDS per block.
// ---------------------------------------------------------------------------
__global__ __launch_bounds__(256) void mlp2r(
    const float* __restrict__ Hp, const float* __restrict__ b1,
    const float* __restrict__ W2, const float* __restrict__ b2,
    const float* __restrict__ invDsq,
    float* __restrict__ F0, unsigned* __restrict__ P0, float* __restrict__ nrm0)
{
    __shared__ float sW2[HID_DIM * OUT_DIM];   // 64 KB
    __shared__ float hbuf[4][HID_DIM];         // 4 KB
    int tid  = threadIdx.x;
    int wid  = tid >> 6, lane = tid & 63;
    int row  = blockIdx.x * 4 + wid;
    const size_t PS = (size_t)N_NODES * HID_DIM;

    for (int i = tid; i < HID_DIM * OUT_DIM / 4; i += 256)
        ((float4*)sW2)[i] = ((const float4*)W2)[i];

    const float* hrow = Hp + (size_t)row * HID_DIM + lane * 4;
    float4 s0 = *(const float4*)(hrow);
    float4 s1 = *(const float4*)(hrow + PS);
    float4 s2 = *(const float4*)(hrow + 2 * PS);
    float4 s3 = *(const float4*)(hrow + 3 * PS);
    float4 bb = *(const float4*)(b1 + lane * 4);
    float h0 = fmaxf(s0.x + s1.x + s2.x + s3.x + bb.x, 0.0f);
    float h1 = fmaxf(s0.y + s1.y + s2.y + s3.y + bb.y, 0.0f);
    float h2 = fmaxf(s0.z + s1.z + s2.z + s3.z + bb.z, 0.0f);
    float h3 = fmaxf(s0.w + s1.w + s2.w + s3.w + bb.w, 0.0f);
    __syncthreads();
    hbuf[wid][lane * 4 + 0] = h0;
    hbuf[wid][lane * 4 + 1] = h1;
    hbuf[wid][lane * 4 + 2] = h2;
    hbuf[wid][lane * 4 + 3] = h3;
    __syncthreads();

    float acc = b2[lane];
#pragma unroll 8
    for (int k = 0; k < HID_DIM; k++) {
        acc += hbuf[wid][k] * sW2[k * OUT_DIM + lane];
    }

    size_t o = (size_t)row * OUT_DIM + lane;
    F0[o] = acc;
    float fn = acc * invDsq[row];
    float nrm = fmaxf(sqrtf(wave_reduce_add(fn * fn)), 1e-12f);
    float fu = fn / nrm;
    float fu_hi = __shfl_xor(fu, 1, 64);
    if ((lane & 1) == 0) {
        P0[(size_t)row * 32 + (lane >> 1)] = pack2(fu, fu_hi);
    }
    if (lane == 0) nrm0[row] = nrm;
}

// ---------------------------------------------------------------------------
// ALL 10 propagation steps in ONE persistent kernel with a hand-rolled grid
// barrier (R8's cg::grid_group::sync measured ~85 µs/sync — API overhead;
// a kernel boundary does the same visibility work in ~10 µs, this barrier
// targets ~3-6 µs). 256 blocks x 256 (1 block/CU), 4 waves/block, each wave
// owns ROWS_PER_WAVE=4 rows sequentially. ELL/F0/invD state loaded once and
// held in registers; ELL/F0/norm stay L2-warm across steps inside the kernel.
// Per-row math byte-identical to R11's propagate.
// ---------------------------------------------------------------------------
__global__ __launch_bounds__(256) void propagate_fused(
    unsigned* __restrict__ Pa, unsigned* __restrict__ Pb,
    float* __restrict__ nrmA, float* __restrict__ nrmB,
    const float* __restrict__ F0,
    const int* __restrict__ ell, const int* __restrict__ deg,
    const float* __restrict__ invD, const float* __restrict__ invDsq,
    const float* __restrict__ raw_gamma, float* __restrict__ out,
    int* __restrict__ gcnt)
{
    int tid  = threadIdx.x;
    int wid  = tid >> 6, lane = tid & 63;
    int g    = lane >> 3;              // edge group 0..7
    int sl   = lane & 7;               // feature slice
    int rbase = blockIdx.x * (4 * ROWS_PER_WAVE) + wid * ROWS_PER_WAVE;
    const float inv_am1 = 1.0f / (SCAD_A - 1.0f);

    // persistent per-row invariants
    int   dgA[ROWS_PER_WAVE], npA[ROWS_PER_WAVE];
    int   e0A[ROWS_PER_WAVE], e1A[ROWS_PER_WAVE];
    float iDA[ROWS_PER_WAVE], iDsA[ROWS_PER_WAVE], f0A[ROWS_PER_WAVE][8];
#pragma unroll
    for (int m = 0; m < ROWS_PER_WAVE; m++) {
        int r = rbase + m;
        int dg = deg[r];
        dgA[m] = dg;
        int pad = (dg + 15) & ~15;
        npA[m] = pad >> 4;
        const int* nb = ell + (size_t)r * MAX_DEG;
        e0A[m] = (lane < pad)      ? nb[lane]      : r;
        e1A[m] = (64 + lane < pad) ? nb[64 + lane] : r;
        iDA[m]  = invD[r];
        iDsA[m] = invDsq[r];
        const float4* f04 = (const float4*)(F0 + (size_t)r * OUT_DIM + sl * 8);
        float4 fa = f04[0], fb = f04[1];
        f0A[m][0] = fa.x; f0A[m][1] = fa.y; f0A[m][2] = fa.z; f0A[m][3] = fa.w;
        f0A[m][4] = fb.x; f0A[m][5] = fb.y; f0A[m][6] = fb.z; f0A[m][7] = fb.w;
    }

    for (int k = 0; k < PROP_STEP; k++) {
        const unsigned* __restrict__ Pin = (k & 1) ? Pb : Pa;
        unsigned* __restrict__ Pout      = (k & 1) ? Pa : Pb;
        const float* __restrict__ nIn    = (k & 1) ? nrmB : nrmA;
        float* __restrict__ nOut         = (k & 1) ? nrmA : nrmB;
        float gamma = 2.0f / (1.0f + expf(-raw_gamma[k]));
        float lam_k = fmaxf(gamma / SCAD_A, 1e-8f);
        float tt    = SCAD_A * lam_k;

        for (int m = 0; m < ROWS_PER_WAVE; m++) {
            int r = rbase + m;
            uint4 up = *(const uint4*)(Pin + (size_t)r * 32 + sl * 4);
            float ui[8] = { bflo(up.x), bfhi(up.x), bflo(up.y), bfhi(up.y),
                            bflo(up.z), bfhi(up.z), bflo(up.w), bfhi(up.w) };
            float acc[8] = {};
            float qsum = 0.0f;
            int dg = dgA[m], npair = npA[m];
            int ed0 = e0A[m], ed1 = e1A[m];
            for (int it = 0; it < npair; ++it) {
                int e0 = it * 16 + g;
                int e1 = e0 + 8;
                int src = (it < 4) ? ed0 : ed1;          // wave-uniform select
                int j0 = __shfl(src, e0 & 63, 64);
                int j1 = __shfl(src, e1 & 63, 64);
                uint4 u0 = *(const uint4*)(Pin + (size_t)j0 * 32 + sl * 4);
                uint4 u1 = *(const uint4*)(Pin + (size_t)j1 * 32 + sl * 4);
                float nr0 = nIn[j0];
                float nr1 = nIn[j1];

                float pa = ui[0] * bflo(u0.x) + ui[1] * bfhi(u0.x) + ui[2] * bflo(u0.y) + ui[3] * bfhi(u0.y)
                         + ui[4] * bflo(u0.z) + ui[5] * bfhi(u0.z) + ui[6] * bflo(u0.w) + ui[7] * bfhi(u0.w);
                float pb = ui[0] * bflo(u1.x) + ui[1] * bfhi(u1.x) + ui[2] * bflo(u1.y) + ui[3] * bfhi(u1.y)
                         + ui[4] * bflo(u1.z) + ui[5] * bfhi(u1.z) + ui[6] * bflo(u1.w) + ui[7] * bfhi(u1.w);
                pa += __shfl_xor(pa, 1, 64); pb += __shfl_xor(pb, 1, 64);
                pa += __shfl_xor(pa, 2, 64); pb += __shfl_xor(pb, 2, 64);
                pa += __shfl_xor(pa, 4, 64); pb += __shfl_xor(pb, 4, 64);
                float ya = 1.0f - pa, yb = 1.0f - pb;
                float wa = (ya <= lam_k) ? 1.0f : ((ya <= tt) ? (tt - ya) * inv_am1 / ya : 0.0f);
                float wb = (yb <= lam_k) ? 1.0f : ((yb <= tt) ? (tt - yb) * inv_am1 / yb : 0.0f);
                if (e0 >= dg) wa = 0.0f;
                if (e1 >= dg) wb = 0.0f;
                qsum += wa + wb;                         // Q_hat uses unscaled w
                float wsa = wa * nr0;                    // Fn[j] = Fu[j]*nrm[j]
                float wsb = wb * nr1;
                acc[0] += wsa * bflo(u0.x) + wsb * bflo(u1.x);
                acc[1] += wsa * bfhi(u0.x) + wsb * bfhi(u1.x);
                acc[2] += wsa * bflo(u0.y) + wsb * bflo(u1.y);
                acc[3] += wsa * bfhi(u0.y) + wsb * bfhi(u1.y);
                acc[4] += wsa * bflo(u0.z) + wsb * bflo(u1.z);
                acc[5] += wsa * bfhi(u0.z) + wsb * bfhi(u1.z);
                acc[6] += wsa * bflo(u0.w) + wsb * bflo(u1.w);
                acc[7] += wsa * bfhi(u0.w) + wsb * bfhi(u1.w);
            }

#pragma unroll
            for (int off = 8; off <= 32; off <<= 1) {
#pragma unroll
                for (int q = 0; q < 8; q++) acc[q] += __shfl_xor(acc[q], off, 64);
                qsum += __shfl_xor(qsum, off, 64);
            }

            float iDs = iDsA[m];
            float Qh  = qsum * iDA[m] + LAM_CONST;
            float rQh = 1.0f / Qh;
            float res[8];
#pragma unroll
            for (int q = 0; q < 8; q++) res[q] = (acc[q] * iDs + LAM_CONST * f0A[m][q]) * rQh;

            if (k == PROP_STEP - 1) {
                if (lane < 8) {
                    float4* o4 = (float4*)(out + (size_t)r * OUT_DIM + sl * 8);
                    o4[0] = make_float4(res[0], res[1], res[2], res[3]);
                    o4[1] = make_float4(res[4], res[5], res[6], res[7]);
                }
            } else {
                float fn[8];
                float ssq = 0.0f;
#pragma unroll
                for (int q = 0; q < 8; q++) { fn[q] = res[q] * iDs; ssq += fn[q] * fn[q]; }
                ssq += __shfl_xor(ssq, 1, 64);
                ssq += __shfl_xor(ssq, 2, 64);
                ssq += __shfl_xor(ssq, 4, 64);
                float nrm = fmaxf(sqrtf(ssq), 1e-12f);
                float inv_n = 1.0f / nrm;
                if (lane < 8) {
                    uint4 fuPk;
                    fuPk.x = pack2(fn[0] * inv_n, fn[1] * inv_n);
                    fuPk.y = pack2(fn[2] * inv_n, fn[3] * inv_n);
                    fuPk.z = pack2(fn[4] * inv_n, fn[5] * inv_n);
                    fuPk.w = pack2(fn[6] * inv_n, fn[7] * inv_n);
                    *(uint4*)(Pout + (size_t)r * 32 + sl * 4) = fuPk;
                }
                if (lane == 0) nOut[r] = nrm;
            }
        }
        if (k < PROP_STEP - 1) {
            grid_barrier(gcnt, (k + 1) * PROP_BLOCKS);
        }
    }
}

// ---------------------------------------------------------------------------
extern "C" void kernel_launch(void* const* d_in, const int* in_sizes, int n_in,
                              void* d_out, int out_size, void* d_ws, size_t ws_size,
                              hipStream_t stream)
{
    const float* A  = (const float*)d_in[0];
    const float* F  = (const float*)d_in[1];
    const float* W1 = (const float*)d_in[2];
    const float* b1 = (const float*)d_in[3];
    const float* W2 = (const float*)d_in[4];
    const float* b2 = (const float*)d_in[5];
    const float* rg = (const float*)d_in[6];
    float* out = (float*)d_out;

    // workspace layout (~20.3 MB)
    char* p = (char*)d_ws;
    float* Hp     = (float*)p; p += (size_t)KSPLIT * N_NODES * HID_DIM * 4;  // 16 MB
    float* F0     = (float*)p; p += (size_t)N_NODES * OUT_DIM * 4;           // 1 MB
    unsigned* Pa  = (unsigned*)p; p += (size_t)N_NODES * 32 * 4;             // 512 KB packed Fu
    unsigned* Pb  = (unsigned*)p; p += (size_t)N_NODES * 32 * 4;             // 512 KB
    float* nrmA   = (float*)p; p += (size_t)N_NODES * 4;                     // 16 KB
    float* nrmB   = (float*)p; p += (size_t)N_NODES * 4;
    float* invD   = (float*)p; p += (size_t)N_NODES * 4;
    float* invDsq = (float*)p; p += (size_t)N_NODES * 4;
    int*   deg    = (int*)p;   p += (size_t)N_NODES * 4;
    int*   ell    = (int*)p;   p += (size_t)N_NODES * MAX_DEG * 4;           // 2 MB
    int*   gcnt   = (int*)p;   p += 128;                                     // barrier counter

    // zero the barrier counter (workspace is poisoned 0xAA before each call)
    hipMemsetAsync(gcnt, 0, 128, stream);

    build_mlp1<<<MLP1_BLOCKS + N_NODES, 256, 0, stream>>>(
        A, F, W1, Hp, ell, deg, invD, invDsq);
    mlp2r<<<N_NODES / 4, 256, 0, stream>>>(Hp, b1, W2, b2, invDsq, F0, Pa, nrmA);

    propagate_fused<<<PROP_BLOCKS, 256, 0, stream>>>(
        Pa, Pb, nrmA, nrmB, F0, ell, deg, invD, invDsq, rg, out, gcnt);
}

// Round 13
// 203.854 us; speedup vs baseline: 3.2232x; 3.2232x over previous
//
#include <hip/hip_runtime.h>
#include <hip/hip_bf16.h>

// Problem constants (from reference)
#define N_NODES 4096
#define IN_DIM  512
#define HID_DIM 256
#define OUT_DIM 64
#define PROP_STEP 10
#define MAX_DEG 128            // mean degree ~41; padded to multiple of 16
#define KSPLIT  4              // mlp1 split-K factor
#define MLP1_BLOCKS (64 * 4 * KSPLIT)   // 1024
#define LAM_CONST (1.0f/0.9f - 1.0f)
#define SCAD_A 3.7f

__device__ __forceinline__ ushort f2bf(float f) {
    unsigned u = __float_as_uint(f);
    unsigned r = (u + 0x7FFFu + ((u >> 16) & 1u)) >> 16;  // RNE
    return (ushort)r;
}
__device__ __forceinline__ unsigned pack2(float lo, float hi) {
    return (unsigned)f2bf(lo) | ((unsigned)f2bf(hi) << 16);
}
__device__ __forceinline__ float bflo(unsigned u) { return __uint_as_float(u << 16); }
__device__ __forceinline__ float bfhi(unsigned u) { return __uint_as_float(u & 0xFFFF0000u); }

__device__ __forceinline__ float wave_reduce_add(float v) {
#pragma unroll
    for (int off = 32; off > 0; off >>= 1) v += __shfl_xor(v, off, 64);
    return v;
}

// ---------------------------------------------------------------------------
// Heterogeneous fused kernel: blocks [0, 1024) run the mlp1 split-K GEMM
// (issued FIRST to seed the CUs); blocks [1024, 1024+4096) each build one
// ELL adjacency row from dense fp32 A. Disjoint inputs/outputs; overlap.
// NOTE (measured, R8+R12): in-kernel grid-wide sync costs 55-85 µs/sync on
// MI355X (device-scope fence across 8 non-coherent XCD L2s); a kernel
// boundary does the same visibility work in ~10 µs. Hence the per-step
// dispatch structure below is the OPTIMAL known structure, not a fallback.
// ---------------------------------------------------------------------------
__global__ __launch_bounds__(256) void build_mlp1(
    const float* __restrict__ A, const float* __restrict__ F,
    const float* __restrict__ W1, float* __restrict__ Hp,
    int* __restrict__ ell, int* __restrict__ deg,
    float* __restrict__ invD, float* __restrict__ invDsq)
{
    if (blockIdx.x < MLP1_BLOCKS) {
        __shared__ float sA[16][68];
        __shared__ float sB[16][68];
        int bid = blockIdx.x;
        int t  = threadIdx.x;
        int m0 = (bid & 63) * 64;
        int n0 = ((bid >> 6) & 3) * 64;
        int kp = bid >> 8;                 // 0..3
        int tm = (t & 15) * 4;
        int tn = (t >> 4) * 4;
        int ar = t >> 2;
        int ac = (t & 3) * 4;
        int br = t >> 4;
        int bc = (t & 15) * 4;
        float acc[4][4] = {};
        int k0 = kp * (IN_DIM / KSPLIT);
        for (int kc = k0; kc < k0 + IN_DIM / KSPLIT; kc += 16) {
            float4 va = *(const float4*)(F  + (size_t)(m0 + ar) * IN_DIM + kc + ac);
            float4 vb = *(const float4*)(W1 + (size_t)(kc + br) * HID_DIM + n0 + bc);
            __syncthreads();
            sA[ac + 0][ar] = va.x;
            sA[ac + 1][ar] = va.y;
            sA[ac + 2][ar] = va.z;
            sA[ac + 3][ar] = va.w;
            *(float4*)&sB[br][bc] = vb;
            __syncthreads();
#pragma unroll
            for (int k = 0; k < 16; k++) {
                float4 a = *(const float4*)&sA[k][tm];
                float4 b = *(const float4*)&sB[k][tn];
                acc[0][0] += a.x * b.x; acc[0][1] += a.x * b.y; acc[0][2] += a.x * b.z; acc[0][3] += a.x * b.w;
                acc[1][0] += a.y * b.x; acc[1][1] += a.y * b.y; acc[1][2] += a.y * b.z; acc[1][3] += a.y * b.w;
                acc[2][0] += a.z * b.x; acc[2][1] += a.z * b.y; acc[2][2] += a.z * b.z; acc[2][3] += a.z * b.w;
                acc[3][0] += a.w * b.x; acc[3][1] += a.w * b.y; acc[3][2] += a.w * b.z; acc[3][3] += a.w * b.w;
            }
        }
        float* Hb = Hp + (size_t)kp * N_NODES * HID_DIM;
#pragma unroll
        for (int r = 0; r < 4; r++) {
            *(float4*)&Hb[(size_t)(m0 + tm + r) * HID_DIM + n0 + tn] =
                make_float4(acc[r][0], acc[r][1], acc[r][2], acc[r][3]);
        }
    } else {
        __shared__ int cnt;
        int i = blockIdx.x - MLP1_BLOCKS;
        int t = threadIdx.x;
        if (t == 0) cnt = 0;
        __syncthreads();
        const float4* row = (const float4*)(A + (size_t)i * N_NODES);
        for (int q = t; q < N_NODES / 4; q += 256) {
            float4 v = row[q];
            if (v.x != 0.0f) { int p = atomicAdd(&cnt, 1); if (p < MAX_DEG) ell[i * MAX_DEG + p] = q * 4 + 0; }
            if (v.y != 0.0f) { int p = atomicAdd(&cnt, 1); if (p < MAX_DEG) ell[i * MAX_DEG + p] = q * 4 + 1; }
            if (v.z != 0.0f) { int p = atomicAdd(&cnt, 1); if (p < MAX_DEG) ell[i * MAX_DEG + p] = q * 4 + 2; }
            if (v.w != 0.0f) { int p = atomicAdd(&cnt, 1); if (p < MAX_DEG) ell[i * MAX_DEG + p] = q * 4 + 3; }
        }
        __syncthreads();
        if (t == 0) {
            int c = cnt;
            if (c > MAX_DEG) c = MAX_DEG;
            deg[i] = c;
            int pad = (c + 15) & ~15;
            if (pad > MAX_DEG) pad = MAX_DEG;
            for (int p = c; p < pad; p++) ell[i * MAX_DEG + p] = i;  // self pad, masked later
            float d = (float)(cnt + 1);   // true degree + self loop
            invD[i] = 1.0f / d;
            invDsq[i] = rsqrtf(d);
        }
    }
}

// ---------------------------------------------------------------------------
// Fused reduce+mlp2: h = relu(sum_z Hp[z] + b1); F0 = h @ W2 + b2; + first
// normalize -> packed bf16 Fu row + fp32 norm. W2 staged in LDS per block.
// ---------------------------------------------------------------------------
__global__ __launch_bounds__(256) void mlp2r(
    const float* __restrict__ Hp, const float* __restrict__ b1,
    const float* __restrict__ W2, const float* __restrict__ b2,
    const float* __restrict__ invDsq,
    float* __restrict__ F0, unsigned* __restrict__ P0, float* __restrict__ nrm0)
{
    __shared__ float sW2[HID_DIM * OUT_DIM];   // 64 KB
    __shared__ float hbuf[4][HID_DIM];         // 4 KB
    int tid  = threadIdx.x;
    int wid  = tid >> 6, lane = tid & 63;
    int row  = blockIdx.x * 4 + wid;
    const size_t PS = (size_t)N_NODES * HID_DIM;

    for (int i = tid; i < HID_DIM * OUT_DIM / 4; i += 256)
        ((float4*)sW2)[i] = ((const float4*)W2)[i];

    const float* hrow = Hp + (size_t)row * HID_DIM + lane * 4;
    float4 s0 = *(const float4*)(hrow);
    float4 s1 = *(const float4*)(hrow + PS);
    float4 s2 = *(const float4*)(hrow + 2 * PS);
    float4 s3 = *(const float4*)(hrow + 3 * PS);
    float4 bb = *(const float4*)(b1 + lane * 4);
    float h0 = fmaxf(s0.x + s1.x + s2.x + s3.x + bb.x, 0.0f);
    float h1 = fmaxf(s0.y + s1.y + s2.y + s3.y + bb.y, 0.0f);
    float h2 = fmaxf(s0.z + s1.z + s2.z + s3.z + bb.z, 0.0f);
    float h3 = fmaxf(s0.w + s1.w + s2.w + s3.w + bb.w, 0.0f);
    __syncthreads();
    hbuf[wid][lane * 4 + 0] = h0;
    hbuf[wid][lane * 4 + 1] = h1;
    hbuf[wid][lane * 4 + 2] = h2;
    hbuf[wid][lane * 4 + 3] = h3;
    __syncthreads();

    float acc = b2[lane];
#pragma unroll 8
    for (int k = 0; k < HID_DIM; k++) {
        acc += hbuf[wid][k] * sW2[k * OUT_DIM + lane];
    }

    size_t o = (size_t)row * OUT_DIM + lane;
    F0[o] = acc;
    float fn = acc * invDsq[row];
    float nrm = fmaxf(sqrtf(wave_reduce_add(fn * fn)), 1e-12f);
    float fu = fn / nrm;
    float fu_hi = __shfl_xor(fu, 1, 64);
    if ((lane & 1) == 0) {
        P0[(size_t)row * 32 + (lane >> 1)] = pack2(fu, fu_hi);
    }
    if (lane == 0) nrm0[row] = nrm;
}

// ---------------------------------------------------------------------------
// One propagation step. 1024 blocks x 256: 4 INDEPENDENT single-row waves per
// block (no LDS, no __syncthreads — identical math/waves to R11's 4096x64,
// but 4x fewer workgroups to dispatch per step). 8 lanes per edge group,
// lane sl owns features [8sl,8sl+8). Gather = packed bf16 Fu row (128 B) +
// fp32 norm table; Fn[j] = Fu[j]*nrm[j]. 16 edges per iteration.
// ---------------------------------------------------------------------------
__global__ __launch_bounds__(256, 4) void propagate(
    const unsigned* __restrict__ Pin, const float* __restrict__ nrmIn,
    const float* __restrict__ F0,
    const int* __restrict__ ell, const int* __restrict__ deg,
    const float* __restrict__ invD, const float* __restrict__ invDsq,
    const float* __restrict__ raw_gamma, int step,
    unsigned* __restrict__ Pout, float* __restrict__ nrmOut,
    float* __restrict__ FcOut, int writeNext, int writeOut)
{
    int lane = threadIdx.x & 63;
    int wid  = threadIdx.x >> 6;
    int r    = __builtin_amdgcn_readfirstlane(blockIdx.x * 4 + wid);
    int g    = lane >> 3;              // edge group 0..7
    int sl   = lane & 7;               // feature slice
    const float inv_am1 = 1.0f / (SCAD_A - 1.0f);

    float gamma = 2.0f / (1.0f + expf(-raw_gamma[step]));
    float lam_k = fmaxf(gamma / SCAD_A, 1e-8f);
    float tt    = SCAD_A * lam_k;

    int dg = deg[r];
    int pad = (dg + 15) & ~15;
    int npair = pad >> 4;
    const int* nb = ell + (size_t)r * MAX_DEG;
    int ed0 = (lane < pad)      ? nb[lane]      : r;   // edges 0..63 by lane
    int ed1 = (64 + lane < pad) ? nb[64 + lane] : r;   // edges 64..127 by lane

    uint4 up = *(const uint4*)(Pin + (size_t)r * 32 + sl * 4);
    float ui[8] = { bflo(up.x), bfhi(up.x), bflo(up.y), bfhi(up.y),
                    bflo(up.z), bfhi(up.z), bflo(up.w), bfhi(up.w) };

    float acc[8] = {};
    float qsum = 0.0f;
    for (int it = 0; it < npair; ++it) {
        int e0 = it * 16 + g;
        int e1 = e0 + 8;
        int src = (it < 4) ? ed0 : ed1;              // wave-uniform select
        int j0 = __shfl(src, e0 & 63, 64);
        int j1 = __shfl(src, e1 & 63, 64);
        uint4 u0 = *(const uint4*)(Pin + (size_t)j0 * 32 + sl * 4);
        uint4 u1 = *(const uint4*)(Pin + (size_t)j1 * 32 + sl * 4);
        float nr0 = nrmIn[j0];
        float nr1 = nrmIn[j1];

        float pa = ui[0] * bflo(u0.x) + ui[1] * bfhi(u0.x) + ui[2] * bflo(u0.y) + ui[3] * bfhi(u0.y)
                 + ui[4] * bflo(u0.z) + ui[5] * bfhi(u0.z) + ui[6] * bflo(u0.w) + ui[7] * bfhi(u0.w);
        float pb = ui[0] * bflo(u1.x) + ui[1] * bfhi(u1.x) + ui[2] * bflo(u1.y) + ui[3] * bfhi(u1.y)
                 + ui[4] * bflo(u1.z) + ui[5] * bfhi(u1.z) + ui[6] * bflo(u1.w) + ui[7] * bfhi(u1.w);
        pa += __shfl_xor(pa, 1, 64); pb += __shfl_xor(pb, 1, 64);
        pa += __shfl_xor(pa, 2, 64); pb += __shfl_xor(pb, 2, 64);
        pa += __shfl_xor(pa, 4, 64); pb += __shfl_xor(pb, 4, 64);
        float ya = 1.0f - pa, yb = 1.0f - pb;
        float wa = (ya <= lam_k) ? 1.0f : ((ya <= tt) ? (tt - ya) * inv_am1 / ya : 0.0f);
        float wb = (yb <= lam_k) ? 1.0f : ((yb <= tt) ? (tt - yb) * inv_am1 / yb : 0.0f);
        if (e0 >= dg) wa = 0.0f;
        if (e1 >= dg) wb = 0.0f;
        qsum += wa + wb;                             // Q_hat uses unscaled w
        float wsa = wa * nr0;                        // Fn[j] = Fu[j]*nrm[j]
        float wsb = wb * nr1;
        acc[0] += wsa * bflo(u0.x) + wsb * bflo(u1.x);
        acc[1] += wsa * bfhi(u0.x) + wsb * bfhi(u1.x);
        acc[2] += wsa * bflo(u0.y) + wsb * bflo(u1.y);
        acc[3] += wsa * bfhi(u0.y) + wsb * bfhi(u1.y);
        acc[4] += wsa * bflo(u0.z) + wsb * bflo(u1.z);
        acc[5] += wsa * bfhi(u0.z) + wsb * bfhi(u1.z);
        acc[6] += wsa * bflo(u0.w) + wsb * bflo(u1.w);
        acc[7] += wsa * bfhi(u0.w) + wsb * bfhi(u1.w);
    }

    // cross-group reduction: every lane ends with the full row sums
#pragma unroll
    for (int off = 8; off <= 32; off <<= 1) {
#pragma unroll
        for (int q = 0; q < 8; q++) acc[q] += __shfl_xor(acc[q], off, 64);
        qsum += __shfl_xor(qsum, off, 64);
    }

    float iDs = invDsq[r];
    float Qh  = qsum * invD[r] + LAM_CONST;
    float rQh = 1.0f / Qh;
    const float4* f04 = (const float4*)(F0 + (size_t)r * OUT_DIM + sl * 8);
    float4 f0a = f04[0], f0b = f04[1];
    float f0v[8] = { f0a.x, f0a.y, f0a.z, f0a.w, f0b.x, f0b.y, f0b.z, f0b.w };
    float res[8];
#pragma unroll
    for (int q = 0; q < 8; q++) res[q] = (acc[q] * iDs + LAM_CONST * f0v[q]) * rQh;

    if (writeOut && lane < 8) {
        float4* o4 = (float4*)(FcOut + (size_t)r * OUT_DIM + sl * 8);
        o4[0] = make_float4(res[0], res[1], res[2], res[3]);
        o4[1] = make_float4(res[4], res[5], res[6], res[7]);
    }
    if (writeNext) {
        float fn[8];
        float ssq = 0.0f;
#pragma unroll
        for (int q = 0; q < 8; q++) { fn[q] = res[q] * iDs; ssq += fn[q] * fn[q]; }
        ssq += __shfl_xor(ssq, 1, 64);   // lanes 0..7 mix among themselves
        ssq += __shfl_xor(ssq, 2, 64);
        ssq += __shfl_xor(ssq, 4, 64);
        float nrm = fmaxf(sqrtf(ssq), 1e-12f);
        float inv_n = 1.0f / nrm;
        if (lane < 8) {
            uint4 fuPk;
            fuPk.x = pack2(fn[0] * inv_n, fn[1] * inv_n);
            fuPk.y = pack2(fn[2] * inv_n, fn[3] * inv_n);
            fuPk.z = pack2(fn[4] * inv_n, fn[5] * inv_n);
            fuPk.w = pack2(fn[6] * inv_n, fn[7] * inv_n);
            *(uint4*)(Pout + (size_t)r * 32 + sl * 4) = fuPk;
        }
        if (lane == 0) nrmOut[r] = nrm;
    }
}

// ---------------------------------------------------------------------------
extern "C" void kernel_launch(void* const* d_in, const int* in_sizes, int n_in,
                              void* d_out, int out_size, void* d_ws, size_t ws_size,
                              hipStream_t stream)
{
    const float* A  = (const float*)d_in[0];
    const float* F  = (const float*)d_in[1];
    const float* W1 = (const float*)d_in[2];
    const float* b1 = (const float*)d_in[3];
    const float* W2 = (const float*)d_in[4];
    const float* b2 = (const float*)d_in[5];
    const float* rg = (const float*)d_in[6];
    float* out = (float*)d_out;

    // workspace layout (~20.3 MB)
    char* p = (char*)d_ws;
    float* Hp     = (float*)p; p += (size_t)KSPLIT * N_NODES * HID_DIM * 4;  // 16 MB
    float* F0     = (float*)p; p += (size_t)N_NODES * OUT_DIM * 4;           // 1 MB
    unsigned* Pa  = (unsigned*)p; p += (size_t)N_NODES * 32 * 4;             // 512 KB packed Fu
    unsigned* Pb  = (unsigned*)p; p += (size_t)N_NODES * 32 * 4;             // 512 KB
    float* nrmA   = (float*)p; p += (size_t)N_NODES * 4;                     // 16 KB
    float* nrmB   = (float*)p; p += (size_t)N_NODES * 4;
    float* invD   = (float*)p; p += (size_t)N_NODES * 4;
    float* invDsq = (float*)p; p += (size_t)N_NODES * 4;
    int*   deg    = (int*)p;   p += (size_t)N_NODES * 4;
    int*   ell    = (int*)p;   p += (size_t)N_NODES * MAX_DEG * 4;           // 2 MB

    build_mlp1<<<MLP1_BLOCKS + N_NODES, 256, 0, stream>>>(
        A, F, W1, Hp, ell, deg, invD, invDsq);
    mlp2r<<<N_NODES / 4, 256, 0, stream>>>(Hp, b1, W2, b2, invDsq, F0, Pa, nrmA);

    for (int k = 0; k < PROP_STEP; k++) {
        unsigned* Pin   = (k & 1) ? Pb : Pa;
        unsigned* Pout  = (k & 1) ? Pa : Pb;
        float* nIn      = (k & 1) ? nrmB : nrmA;
        float* nOut     = (k & 1) ? nrmA : nrmB;
        int last = (k == PROP_STEP - 1);
        propagate<<<N_NODES / 4, 256, 0, stream>>>(
            Pin, nIn, F0, ell, deg, invD, invDsq, rg, k,
            Pout, nOut, out, !last, last);
    }
}